// Round 7
// baseline (437.639 us; speedup 1.0000x reference)
//
#include <hip/hip_runtime.h>

typedef __attribute__((ext_vector_type(8))) short short8;
typedef __attribute__((ext_vector_type(4))) float floatx4;

// ---------------- constants ----------------
#define FH 96
#define FW 312
#define FC 256
#define NP 25281
#define NCELL 7
#define KDIM 1792

__device__ __forceinline__ unsigned short f2bf(float x) {
    union { float f; unsigned u; } v; v.f = x;
    return (unsigned short)((v.u + 0x7fffu + ((v.u >> 16) & 1u)) >> 16);
}
__device__ __forceinline__ float clip1(float v) { return fminf(fmaxf(v, -1.f), 1.f); }
__device__ __forceinline__ int   rfl (int x)   { return __builtin_amdgcn_readfirstlane(x); }
__device__ __forceinline__ float rflf(float x) { return __int_as_float(__builtin_amdgcn_readfirstlane(__float_as_int(x))); }

struct __attribute__((packed, aligned(4))) f4u { float x, y, z, w; };

// ---------------- K1: x-cumsum + transpose to iit[y][x][c] ----------------
__global__ __launch_bounds__(256) void k_xscanT(const float* __restrict__ f, float* __restrict__ iit) {
    __shared__ float sl[32][313];
    const int tid = threadIdx.x, lane = tid & 63, wv = tid >> 6;
    const int y = blockIdx.x, cb = blockIdx.y * 32;
    for (int cr = wv * 8; cr < wv * 8 + 8; ++cr) {
        const float* src = f + (size_t)(cb + cr) * (FH * FW) + y * FW;
#pragma unroll
        for (int xb = 0; xb < FW; xb += 64) {
            const int x = xb + lane;
            if (x < FW) sl[cr][x] = src[x];
        }
    }
    __syncthreads();
    for (int cr = wv * 8; cr < wv * 8 + 8; ++cr) {
        float carry = 0.f;
#pragma unroll
        for (int xb = 0; xb < FW; xb += 64) {
            const int x = xb + lane;
            float v = (x < FW) ? sl[cr][x] : 0.f;
#pragma unroll
            for (int d = 1; d < 64; d <<= 1) {
                float s = __shfl_up(v, d, 64);
                if (lane >= d) v += s;
            }
            v += carry;
            if (x < FW) sl[cr][x] = v;
            carry = __shfl(v, 63, 64);
        }
    }
    __syncthreads();
    const int cw = lane & 31, xo = lane >> 5;
    for (int xi = wv * 2; xi < FW; xi += 8) {
        const int xx = xi + xo;
        iit[(size_t)(y * FW + xx) * FC + cb + cw] = sl[cw][xx];
    }
}

// ---------------- K1b: y-cumsum in place, single pass, batched-8 ----------------
__global__ __launch_bounds__(256) void k_ysum(float* __restrict__ iit) {
    const int x = blockIdx.x;
    float* base = iit + (size_t)x * FC + threadIdx.x;
    float sum = 0.f;
#pragma unroll 1
    for (int yb = 0; yb < FH; yb += 8) {
        float v0 = base[(size_t)(yb + 0) * (FW * FC)];
        float v1 = base[(size_t)(yb + 1) * (FW * FC)];
        float v2 = base[(size_t)(yb + 2) * (FW * FC)];
        float v3 = base[(size_t)(yb + 3) * (FW * FC)];
        float v4 = base[(size_t)(yb + 4) * (FW * FC)];
        float v5 = base[(size_t)(yb + 5) * (FW * FC)];
        float v6 = base[(size_t)(yb + 6) * (FW * FC)];
        float v7 = base[(size_t)(yb + 7) * (FW * FC)];
        sum += v0; base[(size_t)(yb + 0) * (FW * FC)] = sum;
        sum += v1; base[(size_t)(yb + 1) * (FW * FC)] = sum;
        sum += v2; base[(size_t)(yb + 2) * (FW * FC)] = sum;
        sum += v3; base[(size_t)(yb + 3) * (FW * FC)] = sum;
        sum += v4; base[(size_t)(yb + 4) * (FW * FC)] = sum;
        sum += v5; base[(size_t)(yb + 5) * (FW * FC)] = sum;
        sum += v6; base[(size_t)(yb + 6) * (FW * FC)] = sum;
        sum += v7; base[(size_t)(yb + 7) * (FW * FC)] = sum;
    }
}

// ---------------- K2: x tables | y dedup tables | W repack (chunked K-order) ----------------
__global__ __launch_bounds__(256) void k_prep(const float* __restrict__ W, unsigned short* __restrict__ B2,
                       int4* __restrict__ XTc, float4* __restrict__ XTw,
                       float* __restrict__ YRt, int* __restrict__ Rd) {
    const int b = blockIdx.x;
    const int tid = threadIdx.x, lane = tid & 63, wv = tid >> 6;
    const float step = 80.f / 159.f;
    if (b < 99) {
        // X tap table (per p), inv(xd) folded into weights
        const int p = b * 256 + tid;
        if (p < NP) {
            const int d = p / 159, w = p - d * 159;
            const float z0 = 1.f + d * step, z1 = z0 + step;
            const float xa = -40.f + w * step, xb = xa + step;
            const float n00 = clip1((1000.f * xa + 1248.f * z0) / z0 * (2.f / 2496.f) - 1.f);
            const float n10 = clip1((1000.f * xa + 1248.f * z1) / z1 * (2.f / 2496.f) - 1.f);
            const float n01 = clip1((1000.f * xb + 1248.f * z0) / z0 * (2.f / 2496.f) - 1.f);
            const float n11 = clip1((1000.f * xb + 1248.f * z1) / z1 * (2.f / 2496.f) - 1.f);
            const float xmin = fminf(n00, n10);
            const float xmax = fmaxf(n11, n01);
            const float pa = (xmin + 1.f) * (0.5f * FW) - 0.5f;
            const float pb = (xmax + 1.f) * (0.5f * FW) - 0.5f;
            const float fa = floorf(pa), fb = floorf(pb);
            const float wa = pa - fa, wb = pb - fb;
            const int a0 = (int)fa, b0 = (int)fb;
            const float xd = xmax - xmin;
            const float invx = (xd > 0.f) ? (1.f / xd) : 0.f;
            int   cc[4] = { a0, a0 + 1, b0, b0 + 1 };
            float ww[4] = { -(1.f - wa), -wa, (1.f - wb), wb };
#pragma unroll
            for (int i = 0; i < 4; ++i) {
                if (cc[i] < 0 || cc[i] >= FW) { cc[i] = 0; ww[i] = 0.f; }
                ww[i] *= invx;
            }
            XTc[p] = make_int4(cc[0], cc[1], cc[2], cc[3]);
            XTw[p] = make_float4(ww[0], ww[1], ww[2], ww[3]);
        }
    } else if (b < 139) {
        // per-d deduplicated y-row tables: one wave per d; lane t<28 = (kcell=t>>2, tap=t&3)
        const int d = (b - 99) * 4 + wv;
        if (d < 159) {
            const int t = lane;
            const int kcell = (t >> 2) & 7;
            const int tap = t & 3;
            const float z0 = 1.f + d * step, z1 = z0 + step;
            const float ya = -2.f + 0.5f * kcell, yb2 = ya + 0.5f;
            const float m0 = clip1((1000.f * ya  + 384.f * z0) / z0 * (2.f / 768.f) - 1.f);
            const float m1 = clip1((1000.f * ya  + 384.f * z1) / z1 * (2.f / 768.f) - 1.f);
            const float M0 = clip1((1000.f * yb2 + 384.f * z0) / z0 * (2.f / 768.f) - 1.f);
            const float M1 = clip1((1000.f * yb2 + 384.f * z1) / z1 * (2.f / 768.f) - 1.f);
            const float ymin = fminf(m0, m1);
            const float ymax = fmaxf(M0, M1);
            const float yd = ymax - ymin;
            const float invy = (yd > 0.f) ? (1.f / (yd * (FH * FW * 0.25f))) : 0.f;
            const float pa = (ymin + 1.f) * (0.5f * FH) - 0.5f;
            const float pb = (ymax + 1.f) * (0.5f * FH) - 0.5f;
            const float fa = floorf(pa), fb = floorf(pb);
            const float wa = pa - fa, wb = pb - fb;
            int row; float w;
            if      (tap == 0) { row = (int)fa;     w = -(1.f - wa); }
            else if (tap == 1) { row = (int)fa + 1; w = -wa; }
            else if (tap == 2) { row = (int)fb;     w =  (1.f - wb); }
            else               { row = (int)fb + 1; w =  wb; }
            w *= invy;
            const bool valid = (t < 28) && (row >= 0) && (row < FH) && (w != 0.f);
            if (!valid) { row = 0; w = 0.f; }
            int first = 63;
#pragma unroll
            for (int j = 0; j < 28; ++j) {
                const int rj = __shfl(row, j, 64);
                if (rj == row && j < first) first = j;
            }
            const bool leader = (t < 28) && (first == t);
            const unsigned long long mask = __ballot(leader);
            const int slot = (int)__popcll(mask & ((1ull << t) - 1ull));
            const int Rn = (int)__popcll(mask);
            float s0 = 0.f, s1 = 0.f, s2 = 0.f, s3 = 0.f, s4 = 0.f, s5 = 0.f, s6 = 0.f;
#pragma unroll
            for (int j = 0; j < 28; ++j) {
                const int rj = __shfl(row, j, 64);
                const float wj = __shfl(w, j, 64);
                const float add = (rj == row) ? wj : 0.f;
                const int kj = j >> 2;
                if      (kj == 0) s0 += add;
                else if (kj == 1) s1 += add;
                else if (kj == 2) s2 += add;
                else if (kj == 3) s3 += add;
                else if (kj == 4) s4 += add;
                else if (kj == 5) s5 += add;
                else              s6 += add;
            }
            if (leader) {
                float* rec = YRt + ((size_t)d * 28 + slot) * 8;
                rec[0] = s0; rec[1] = s1; rec[2] = s2; rec[3] = s3;
                rec[4] = s4; rec[5] = s5; rec[6] = s6;
                ((int*)rec)[7] = row;
            }
            if (t == 0) Rd[d] = Rn;
        }
    } else {
        // B2 chunked order: e = ((s*16 + nt)*64 + lane)*8 + j, s = cc*14 + kc*2 + ks2
        // element = W[n][c*7+kc], n = nt*16+(lane&15), c = cc*64 + ks2*32 + ((lane>>4)&3)*8 + j
        const int e = (b - 139) * 256 + tid;              // < 458752
        const int j = e & 7, ln = (e >> 3) & 63, nt = (e >> 9) & 15, s = e >> 13;
        const int ks2 = s & 1, t7 = s >> 1;
        const int kc = t7 % 7, cc = t7 / 7;
        const int n = nt * 16 + (ln & 15);
        const int c = cc * 64 + ks2 * 32 + ((ln >> 4) & 3) * 8 + j;
        B2[e] = f2bf(W[n * KDIM + c * NCELL + kc]);
    }
}

// ---------------- K3: chunked dedup-gather + MFMA GEMM + bias + relu ----------------
// 4 channel-chunks of 64; per chunk the per-XCD iit working set is ~L2-resident.
// Wave lane layout in gather: g=lane>>4 picks one of 4 x-taps, l=lane&15 picks 4 channels.
__global__ __launch_bounds__(256, 4) void k_fused(
    const float* __restrict__ iit, const unsigned short* __restrict__ B2,
    const int4* __restrict__ XTc, const float4* __restrict__ XTw,
    const float* __restrict__ YRt, const int* __restrict__ Rd,
    const float* __restrict__ bias, float* __restrict__ out)
{
    __shared__ unsigned short As[32][452];   // 32 p-rows x (7*64 bf16 + 4 pad): stride 226 words = 2 mod 32
    __shared__ float ytab[2 * 28 * 8];       // y-row tables for the block's <=2 d values
    __shared__ int   xtc4[32 * 4];
    __shared__ float xtw4[32 * 4];
    __shared__ int   rnrow[32];
    __shared__ int   ybrow[32];

    const int tid = threadIdx.x, lane = tid & 63, wv = tid >> 6;
    const int b = blockIdx.x;
    const int L = (b & 7) * 99 + (b >> 3);   // XCD swizzle: 792 = 8 x 99
    const int p0 = L * 32;
    const int q = lane >> 4, r = lane & 15;
    const int d0 = (p0 < NP ? p0 : (NP - 1)) / 159;
    const int pme = (p0 + 31 < NP) ? (p0 + 31) : (NP - 1);
    const int d1 = pme / 159;

    // ---- block-level table preload ----
    if (tid < 32) {
        const int p = (p0 + tid < NP) ? (p0 + tid) : (NP - 1);
        const int4  c4 = XTc[p];
        const float4 w4 = XTw[p];
        *(int4*)&xtc4[tid * 4] = c4;
        *(float4*)&xtw4[tid * 4] = w4;
        const int dd = p / 159;
        rnrow[tid] = Rd[dd];
        ybrow[tid] = (dd == d0) ? 0 : 224;
    }
    for (int e = tid; e < 448; e += 256) {
        const int di = e / 224, o = e - di * 224;
        const int dsel = di ? d1 : d0;
        ytab[e] = YRt[(size_t)dsel * 224 + o];
    }
    __syncthreads();

    floatx4 acc0[4], acc1[4];
#pragma unroll
    for (int nt = 0; nt < 4; ++nt) { acc0[nt] = (floatx4){0.f,0.f,0.f,0.f}; acc1[nt] = (floatx4){0.f,0.f,0.f,0.f}; }

    for (int cc = 0; cc < 4; ++cc) {
        // ---- gather chunk cc: wave wv builds p-rows [wv*8, wv*8+8) ----
#pragma unroll 1
        for (int i = 0; i < 8; ++i) {
            const int pr = wv * 8 + i;
            const int4  ci = *(const int4*)&xtc4[pr * 4];
            const float4 wx = *(const float4*)&xtw4[pr * 4];
            const int   cg  = (q == 0) ? ci.x : (q == 1) ? ci.y : (q == 2) ? ci.z : ci.w;
            const float wxg = (q == 0) ? wx.x : (q == 1) ? wx.y : (q == 2) ? wx.z : wx.w;
            const int off = cg * FC + cc * 64 + r * 4;
            const int Rn = rfl(rnrow[pr]);
            const int yb = rfl(ybrow[pr]);
            float4 a0 = make_float4(0.f,0.f,0.f,0.f), a1 = a0, a2 = a0, a3 = a0, a4 = a0, a5 = a0, a6 = a0;
#pragma unroll 2
            for (int j = 0; j < Rn; ++j) {
                const float4 w1 = *(const float4*)&ytab[yb + j * 8];
                const float4 w2 = *(const float4*)&ytab[yb + j * 8 + 4];
                const int rr = rfl(__float_as_int(w2.w));
                const float4 v = *(const float4*)(iit + (size_t)(rr * FW) * FC + off);
                a0.x += w1.x * v.x; a0.y += w1.x * v.y; a0.z += w1.x * v.z; a0.w += w1.x * v.w;
                a1.x += w1.y * v.x; a1.y += w1.y * v.y; a1.z += w1.y * v.z; a1.w += w1.y * v.w;
                a2.x += w1.z * v.x; a2.y += w1.z * v.y; a2.z += w1.z * v.z; a2.w += w1.z * v.w;
                a3.x += w1.w * v.x; a3.y += w1.w * v.y; a3.z += w1.w * v.z; a3.w += w1.w * v.w;
                a4.x += w2.x * v.x; a4.y += w2.x * v.y; a4.z += w2.x * v.z; a4.w += w2.x * v.w;
                a5.x += w2.y * v.x; a5.y += w2.y * v.y; a5.z += w2.y * v.z; a5.w += w2.y * v.w;
                a6.x += w2.z * v.x; a6.y += w2.z * v.y; a6.z += w2.z * v.z; a6.w += w2.z * v.w;
            }
            // premultiply by my tap weight, then xor-reduce across the 4 tap groups
#define RED(A) { A.x *= wxg; A.y *= wxg; A.z *= wxg; A.w *= wxg; \
                 A.x += __shfl_xor(A.x, 16, 64); A.y += __shfl_xor(A.y, 16, 64); \
                 A.z += __shfl_xor(A.z, 16, 64); A.w += __shfl_xor(A.w, 16, 64); \
                 A.x += __shfl_xor(A.x, 32, 64); A.y += __shfl_xor(A.y, 32, 64); \
                 A.z += __shfl_xor(A.z, 32, 64); A.w += __shfl_xor(A.w, 32, 64); }
            RED(a0) RED(a1) RED(a2) RED(a3) RED(a4) RED(a5) RED(a6)
#undef RED
            if (lane < 16) {
                const int wb = r * 4;
#define PK(A) make_uint2((unsigned)f2bf(A.x) | ((unsigned)f2bf(A.y) << 16), \
                         (unsigned)f2bf(A.z) | ((unsigned)f2bf(A.w) << 16))
                *(uint2*)&As[pr][0 * 64 + wb] = PK(a0);
                *(uint2*)&As[pr][1 * 64 + wb] = PK(a1);
                *(uint2*)&As[pr][2 * 64 + wb] = PK(a2);
                *(uint2*)&As[pr][3 * 64 + wb] = PK(a3);
                *(uint2*)&As[pr][4 * 64 + wb] = PK(a4);
                *(uint2*)&As[pr][5 * 64 + wb] = PK(a5);
                *(uint2*)&As[pr][6 * 64 + wb] = PK(a6);
#undef PK
            }
        }
        __syncthreads();

        // ---- MFMA for this chunk: 14 K-steps of 32; wave wv owns n-cols [wv*64, wv*64+64) ----
#pragma unroll
        for (int kc2 = 0; kc2 < 14; ++kc2) {
            const int s = cc * 14 + kc2;
            const short8 af0 = *(const short8*)&As[r     ][kc2 * 32 + q * 8];
            const short8 af1 = *(const short8*)&As[16 + r][kc2 * 32 + q * 8];
            const unsigned short* bs = B2 + (size_t)(((s * 16) + (wv * 4)) * 64 + lane) * 8;
            const short8 bf0 = *(const short8*)(bs);
            const short8 bf1 = *(const short8*)(bs + 512);
            const short8 bf2 = *(const short8*)(bs + 1024);
            const short8 bf3 = *(const short8*)(bs + 1536);
            acc0[0] = __builtin_amdgcn_mfma_f32_16x16x32_bf16(af0, bf0, acc0[0], 0, 0, 0);
            acc0[1] = __builtin_amdgcn_mfma_f32_16x16x32_bf16(af0, bf1, acc0[1], 0, 0, 0);
            acc0[2] = __builtin_amdgcn_mfma_f32_16x16x32_bf16(af0, bf2, acc0[2], 0, 0, 0);
            acc0[3] = __builtin_amdgcn_mfma_f32_16x16x32_bf16(af0, bf3, acc0[3], 0, 0, 0);
            acc1[0] = __builtin_amdgcn_mfma_f32_16x16x32_bf16(af1, bf0, acc1[0], 0, 0, 0);
            acc1[1] = __builtin_amdgcn_mfma_f32_16x16x32_bf16(af1, bf1, acc1[1], 0, 0, 0);
            acc1[2] = __builtin_amdgcn_mfma_f32_16x16x32_bf16(af1, bf2, acc1[2], 0, 0, 0);
            acc1[3] = __builtin_amdgcn_mfma_f32_16x16x32_bf16(af1, bf3, acc1[3], 0, 0, 0);
        }
        __syncthreads();
    }

    // ---- epilogue: D layout col=lane&15, row=(lane>>4)*4+reg; float4 stores ----
#pragma unroll
    for (int nt = 0; nt < 4; ++nt) {
        const int co = wv * 64 + nt * 16 + r;
        const float bs = bias[co];
#pragma unroll
        for (int mt = 0; mt < 2; ++mt) {
            const floatx4 av = mt ? acc1[nt] : acc0[nt];
            const int pb = p0 + mt * 16 + q * 4;
            float* op = out + (size_t)co * NP + pb;
            if (pb + 4 <= NP) {
                f4u vv;
                vv.x = fmaxf(av[0] + bs, 0.f);
                vv.y = fmaxf(av[1] + bs, 0.f);
                vv.z = fmaxf(av[2] + bs, 0.f);
                vv.w = fmaxf(av[3] + bs, 0.f);
                *(f4u*)op = vv;
            } else {
#pragma unroll
                for (int e2 = 0; e2 < 4; ++e2)
                    if (pb + e2 < NP) op[e2] = fmaxf(av[e2] + bs, 0.f);
            }
        }
    }
}

// ---------------- launch ----------------
extern "C" void kernel_launch(void* const* d_in, const int* in_sizes, int n_in,
                              void* d_out, int out_size, void* d_ws, size_t ws_size,
                              hipStream_t stream) {
    (void)in_sizes; (void)n_in; (void)out_size; (void)ws_size;
    const float* features = (const float*)d_in[0];
    const float* W_lin    = (const float*)d_in[4];
    const float* b_lin    = (const float*)d_in[5];
    float* out = (float*)d_out;
    char* ws = (char*)d_ws;

    float*          iit = (float*)(ws + 0);                 // 30,670,848 B
    unsigned short* B2  = (unsigned short*)(ws + 30670848); //    917,504
    int4*   XTc = (int4*)  (ws + 31588352);                 //    405,504
    float4* XTw = (float4*)(ws + 31993856);                 //    405,504
    float*  YRt = (float*) (ws + 32399360);                 //    142,464 (159*28*8 floats)
    int*    Rd  = (int*)   (ws + 32541824);                 //        640

    k_xscanT<<<dim3(96, 8), 256, 0, stream>>>(features, iit);
    k_ysum  <<<312, 256, 0, stream>>>(iit);
    k_prep  <<<1931, 256, 0, stream>>>(W_lin, B2, XTc, XTw, YRt, Rd);
    k_fused <<<792, 256, 0, stream>>>(iit, B2, XTc, XTw, YRt, Rd, b_lin, out);
}

// Round 8
// 263.246 us; speedup vs baseline: 1.6625x; 1.6625x over previous
//
#include <hip/hip_runtime.h>

typedef __attribute__((ext_vector_type(8))) short short8;
typedef __attribute__((ext_vector_type(4))) float floatx4;

// ---------------- constants ----------------
#define FH 96
#define FW 312
#define FC 256
#define NP 25281
#define NPR 25344          // NP rounded to 64
#define NCELL 7
#define KDIM 1792

__device__ __forceinline__ unsigned short f2bf(float x) {
    union { float f; unsigned u; } v; v.f = x;
    return (unsigned short)((v.u + 0x7fffu + ((v.u >> 16) & 1u)) >> 16);
}
__device__ __forceinline__ float clip1(float v) { return fminf(fmaxf(v, -1.f), 1.f); }
__device__ __forceinline__ int   rfl (int x)   { return __builtin_amdgcn_readfirstlane(x); }
__device__ __forceinline__ float rflf(float x) { return __int_as_float(__builtin_amdgcn_readfirstlane(__float_as_int(x))); }

struct __attribute__((packed, aligned(4))) f4u { float x, y, z, w; };

// ---------------- K1: x-cumsum + transpose to iit[y][x][c] ----------------
__global__ __launch_bounds__(256) void k_xscanT(const float* __restrict__ f, float* __restrict__ iit) {
    __shared__ float sl[32][313];
    const int tid = threadIdx.x, lane = tid & 63, wv = tid >> 6;
    const int y = blockIdx.x, cb = blockIdx.y * 32;
    for (int cr = wv * 8; cr < wv * 8 + 8; ++cr) {
        const float* src = f + (size_t)(cb + cr) * (FH * FW) + y * FW;
#pragma unroll
        for (int xb = 0; xb < FW; xb += 64) {
            const int x = xb + lane;
            if (x < FW) sl[cr][x] = src[x];
        }
    }
    __syncthreads();
    for (int cr = wv * 8; cr < wv * 8 + 8; ++cr) {
        float carry = 0.f;
#pragma unroll
        for (int xb = 0; xb < FW; xb += 64) {
            const int x = xb + lane;
            float v = (x < FW) ? sl[cr][x] : 0.f;
#pragma unroll
            for (int d = 1; d < 64; d <<= 1) {
                float s = __shfl_up(v, d, 64);
                if (lane >= d) v += s;
            }
            v += carry;
            if (x < FW) sl[cr][x] = v;
            carry = __shfl(v, 63, 64);
        }
    }
    __syncthreads();
    const int cw = lane & 31, xo = lane >> 5;
    for (int xi = wv * 2; xi < FW; xi += 8) {
        const int xx = xi + xo;
        iit[(size_t)(y * FW + xx) * FC + cb + cw] = sl[cw][xx];
    }
}

// ---------------- K1b: y-cumsum in place ----------------
__global__ __launch_bounds__(256) void k_ysum(float* __restrict__ iit) {
    const int x = blockIdx.x;
    float* base = iit + (size_t)x * FC + threadIdx.x;
    float sum = 0.f;
#pragma unroll 1
    for (int yb = 0; yb < FH; yb += 8) {
        float v0 = base[(size_t)(yb + 0) * (FW * FC)];
        float v1 = base[(size_t)(yb + 1) * (FW * FC)];
        float v2 = base[(size_t)(yb + 2) * (FW * FC)];
        float v3 = base[(size_t)(yb + 3) * (FW * FC)];
        float v4 = base[(size_t)(yb + 4) * (FW * FC)];
        float v5 = base[(size_t)(yb + 5) * (FW * FC)];
        float v6 = base[(size_t)(yb + 6) * (FW * FC)];
        float v7 = base[(size_t)(yb + 7) * (FW * FC)];
        sum += v0; base[(size_t)(yb + 0) * (FW * FC)] = sum;
        sum += v1; base[(size_t)(yb + 1) * (FW * FC)] = sum;
        sum += v2; base[(size_t)(yb + 2) * (FW * FC)] = sum;
        sum += v3; base[(size_t)(yb + 3) * (FW * FC)] = sum;
        sum += v4; base[(size_t)(yb + 4) * (FW * FC)] = sum;
        sum += v5; base[(size_t)(yb + 5) * (FW * FC)] = sum;
        sum += v6; base[(size_t)(yb + 6) * (FW * FC)] = sum;
        sum += v7; base[(size_t)(yb + 7) * (FW * FC)] = sum;
    }
}

// ---------------- K2: x tables | padded y dedup tables | per-(d,kc) y tables | W repack ----------------
__global__ __launch_bounds__(256) void k_prep(const float* __restrict__ W, unsigned short* __restrict__ B2,
                       int4* __restrict__ XTc, float4* __restrict__ XTw,
                       float* __restrict__ YRt, int* __restrict__ Rd,
                       int4* __restrict__ YTc, float4* __restrict__ YTw) {
    const int b = blockIdx.x;
    const int tid = threadIdx.x, lane = tid & 63, wv = tid >> 6;
    const float step = 80.f / 159.f;
    if (b < 99) {
        // X tap table per p, invx folded into weights
        const int p = b * 256 + tid;
        if (p < NP) {
            const int d = p / 159, w = p - d * 159;
            const float z0 = 1.f + d * step, z1 = z0 + step;
            const float xa = -40.f + w * step, xb = xa + step;
            const float n00 = clip1((1000.f * xa + 1248.f * z0) / z0 * (2.f / 2496.f) - 1.f);
            const float n10 = clip1((1000.f * xa + 1248.f * z1) / z1 * (2.f / 2496.f) - 1.f);
            const float n01 = clip1((1000.f * xb + 1248.f * z0) / z0 * (2.f / 2496.f) - 1.f);
            const float n11 = clip1((1000.f * xb + 1248.f * z1) / z1 * (2.f / 2496.f) - 1.f);
            const float xmin = fminf(n00, n10);
            const float xmax = fmaxf(n11, n01);
            const float pa = (xmin + 1.f) * (0.5f * FW) - 0.5f;
            const float pb = (xmax + 1.f) * (0.5f * FW) - 0.5f;
            const float fa = floorf(pa), fb = floorf(pb);
            const float wa = pa - fa, wb = pb - fb;
            const int a0 = (int)fa, b0 = (int)fb;
            const float xd = xmax - xmin;
            const float invx = (xd > 0.f) ? (1.f / xd) : 0.f;
            int   cc[4] = { a0, a0 + 1, b0, b0 + 1 };
            float ww[4] = { -(1.f - wa), -wa, (1.f - wb), wb };
#pragma unroll
            for (int i = 0; i < 4; ++i) {
                if (cc[i] < 0 || cc[i] >= FW) { cc[i] = 0; ww[i] = 0.f; }
                ww[i] *= invx;
            }
            XTc[p] = make_int4(cc[0], cc[1], cc[2], cc[3]);
            XTw[p] = make_float4(ww[0], ww[1], ww[2], ww[3]);
        }
    } else if (b < 139) {
        // per-d deduplicated + group-4-padded y-row tables; one wave per d
        const int d = (b - 99) * 4 + wv;
        if (d < 159) {
            const int t = lane;
            const int kcell = (t >> 2) & 7;
            const int tap = t & 3;
            const float z0 = 1.f + d * step, z1 = z0 + step;
            const float ya = -2.f + 0.5f * kcell, yb2 = ya + 0.5f;
            const float m0 = clip1((1000.f * ya  + 384.f * z0) / z0 * (2.f / 768.f) - 1.f);
            const float m1 = clip1((1000.f * ya  + 384.f * z1) / z1 * (2.f / 768.f) - 1.f);
            const float M0 = clip1((1000.f * yb2 + 384.f * z0) / z0 * (2.f / 768.f) - 1.f);
            const float M1 = clip1((1000.f * yb2 + 384.f * z1) / z1 * (2.f / 768.f) - 1.f);
            const float ymin = fminf(m0, m1);
            const float ymax = fmaxf(M0, M1);
            const float yd = ymax - ymin;
            const float invy = (yd > 0.f) ? (1.f / (yd * (FH * FW * 0.25f))) : 0.f;
            const float pa = (ymin + 1.f) * (0.5f * FH) - 0.5f;
            const float pb = (ymax + 1.f) * (0.5f * FH) - 0.5f;
            const float fa = floorf(pa), fb = floorf(pb);
            const float wa = pa - fa, wb = pb - fb;
            int row; float w;
            if      (tap == 0) { row = (int)fa;     w = -(1.f - wa); }
            else if (tap == 1) { row = (int)fa + 1; w = -wa; }
            else if (tap == 2) { row = (int)fb;     w =  (1.f - wb); }
            else               { row = (int)fb + 1; w =  wb; }
            w *= invy;
            const bool valid = (t < 28) && (row >= 0) && (row < FH) && (w != 0.f);
            if (!valid) { row = 0; w = 0.f; }
            int first = 63;
#pragma unroll
            for (int j = 0; j < 28; ++j) {
                const int rj = __shfl(row, j, 64);
                if (rj == row && j < first) first = j;
            }
            const bool leader = (t < 28) && (first == t);
            const unsigned long long mask = __ballot(leader);
            const int slot = (int)__popcll(mask & ((1ull << t) - 1ull));
            const int Rn = (int)__popcll(mask);
            const int ng = (Rn + 3) >> 2;
            float s0 = 0.f, s1 = 0.f, s2 = 0.f, s3 = 0.f, s4 = 0.f, s5 = 0.f, s6 = 0.f;
#pragma unroll
            for (int j = 0; j < 28; ++j) {
                const int rj = __shfl(row, j, 64);
                const float wj = __shfl(w, j, 64);
                const float add = (rj == row) ? wj : 0.f;
                const int kj = j >> 2;
                if      (kj == 0) s0 += add;
                else if (kj == 1) s1 += add;
                else if (kj == 2) s2 += add;
                else if (kj == 3) s3 += add;
                else if (kj == 4) s4 += add;
                else if (kj == 5) s5 += add;
                else              s6 += add;
            }
            if (leader) {
                float* rec = YRt + ((size_t)d * 28 + slot) * 8;
                rec[0] = s0; rec[1] = s1; rec[2] = s2; rec[3] = s3;
                rec[4] = s4; rec[5] = s5; rec[6] = s6;
                ((int*)rec)[7] = 0;  // row written below as int
                ((int*)rec)[7] = row;
            }
            if ((t >= Rn) && (t < ng * 4)) {           // zero-pad to full groups
                float* rec = YRt + ((size_t)d * 28 + t) * 8;
                rec[0] = 0.f; rec[1] = 0.f; rec[2] = 0.f; rec[3] = 0.f;
                rec[4] = 0.f; rec[5] = 0.f; rec[6] = 0.f;
                ((int*)rec)[7] = 0;
            }
            if (t == 0) Rd[d] = ng;
        }
    } else if (b < 144) {
        // fallback per-(d,kc) y tables (folded weights) — only used on the C path
        const int p = (b - 139) * 256 + tid;
        if (p < 159 * NCELL) {
            const int d = p / NCELL, k = p - (p / NCELL) * NCELL;
            const float z0 = 1.f + d * step, z1 = z0 + step;
            const float ya = -2.f + 0.5f * k, yb2 = ya + 0.5f;
            const float m0 = clip1((1000.f * ya  + 384.f * z0) / z0 * (2.f / 768.f) - 1.f);
            const float m1 = clip1((1000.f * ya  + 384.f * z1) / z1 * (2.f / 768.f) - 1.f);
            const float M0 = clip1((1000.f * yb2 + 384.f * z0) / z0 * (2.f / 768.f) - 1.f);
            const float M1 = clip1((1000.f * yb2 + 384.f * z1) / z1 * (2.f / 768.f) - 1.f);
            const float ymin = fminf(m0, m1);
            const float ymax = fmaxf(M0, M1);
            const float yd = ymax - ymin;
            const float invy = (yd > 0.f) ? (1.f / (yd * (FH * FW * 0.25f))) : 0.f;
            const float pa = (ymin + 1.f) * (0.5f * FH) - 0.5f;
            const float pb = (ymax + 1.f) * (0.5f * FH) - 0.5f;
            const float fa = floorf(pa), fb = floorf(pb);
            const float wa = pa - fa, wb = pb - fb;
            const int a0 = (int)fa, b0 = (int)fb;
            int   rr[4] = { a0, a0 + 1, b0, b0 + 1 };
            float rw[4] = { -(1.f - wa), -wa, (1.f - wb), wb };
#pragma unroll
            for (int i = 0; i < 4; ++i) {
                if (rr[i] < 0 || rr[i] >= FH) { rr[i] = 0; rw[i] = 0.f; }
                rw[i] *= invy;
            }
            YTc[p] = make_int4(rr[0], rr[1], rr[2], rr[3]);
            YTw[p] = make_float4(rw[0], rw[1], rw[2], rw[3]);
        }
    } else {
        // B2[kc][ks][nt][lane][j] = W[n][c*7+kc], n=nt*16+(lane&15), c=ks*32+((lane>>4)&3)*8+j
        const int e = (b - 144) * 256 + tid;              // < 458752
        const int j = e & 7, ln = (e >> 3) & 63, nt = (e >> 9) & 15, ks = (e >> 13) & 7, kc = e >> 16;
        const int n = nt * 16 + (ln & 15);
        const int c = ks * 32 + ((ln >> 4) & 3) * 8 + j;
        B2[e] = f2bf(W[n * KDIM + c * NCELL + kc]);
    }
}

// ---------------- K3a: dedup gather -> vox[p][kc*256+c] (bf16), one wave per p ----------------
__global__ __launch_bounds__(256, 2) void k_gather(
    const float* __restrict__ iit,
    const int4* __restrict__ XTc, const float4* __restrict__ XTw,
    const float* __restrict__ YRt, const int* __restrict__ Rd,
    unsigned short* __restrict__ vox)
{
    const int tid = threadIdx.x, lane = tid & 63, wv = tid >> 6;
    const int b = blockIdx.x;
    const int L = (b & 7) * 792 + (b >> 3);   // 6336 = 8 x 792
    const int p = L * 4 + wv;
    if (p >= NP) return;                       // wave-uniform
    const int4  xc = XTc[p];
    const float4 xw = XTw[p];
    const int c0 = rfl(xc.x), c1 = rfl(xc.y), c2 = rfl(xc.z), c3 = rfl(xc.w);
    const float wx0 = rflf(xw.x), wx1 = rflf(xw.y), wx2 = rflf(xw.z), wx3 = rflf(xw.w);
    const int dd = p / 159;
    const int ng = rfl(Rd[dd]);
    const float* yt = YRt + (size_t)dd * 224;
    const int lo = lane * 4;
    const int o0 = c0 * FC + lo, o1 = c1 * FC + lo, o2 = c2 * FC + lo, o3 = c3 * FC + lo;

    float4 a0 = make_float4(0.f,0.f,0.f,0.f), a1 = a0, a2 = a0, a3 = a0, a4 = a0, a5 = a0, a6 = a0;

#pragma unroll 1
    for (int g = 0; g < ng; ++g) {
        const float* tp = yt + g * 32;
        const float4 wa0 = *(const float4*)(tp +  0), wb0 = *(const float4*)(tp +  4);
        const float4 wa1 = *(const float4*)(tp +  8), wb1 = *(const float4*)(tp + 12);
        const float4 wa2 = *(const float4*)(tp + 16), wb2 = *(const float4*)(tp + 20);
        const float4 wa3 = *(const float4*)(tp + 24), wb3 = *(const float4*)(tp + 28);
        const int r0 = rfl(__float_as_int(wb0.w));
        const int r1 = rfl(__float_as_int(wb1.w));
        const int r2 = rfl(__float_as_int(wb2.w));
        const int r3 = rfl(__float_as_int(wb3.w));
        const float* rp0 = iit + (size_t)r0 * (FW * FC);
        const float* rp1 = iit + (size_t)r1 * (FW * FC);
        const float* rp2 = iit + (size_t)r2 * (FW * FC);
        const float* rp3 = iit + (size_t)r3 * (FW * FC);
        const float4 t00 = *(const float4*)(rp0 + o0);
        const float4 t01 = *(const float4*)(rp0 + o1);
        const float4 t02 = *(const float4*)(rp0 + o2);
        const float4 t03 = *(const float4*)(rp0 + o3);
        const float4 t10 = *(const float4*)(rp1 + o0);
        const float4 t11 = *(const float4*)(rp1 + o1);
        const float4 t12 = *(const float4*)(rp1 + o2);
        const float4 t13 = *(const float4*)(rp1 + o3);
        const float4 t20 = *(const float4*)(rp2 + o0);
        const float4 t21 = *(const float4*)(rp2 + o1);
        const float4 t22 = *(const float4*)(rp2 + o2);
        const float4 t23 = *(const float4*)(rp2 + o3);
        const float4 t30 = *(const float4*)(rp3 + o0);
        const float4 t31 = *(const float4*)(rp3 + o1);
        const float4 t32 = *(const float4*)(rp3 + o2);
        const float4 t33 = *(const float4*)(rp3 + o3);
#define UCOMB(TA, TB, TC, TD, U) float4 U; \
        U.x = wx0*TA.x + wx1*TB.x + wx2*TC.x + wx3*TD.x; \
        U.y = wx0*TA.y + wx1*TB.y + wx2*TC.y + wx3*TD.y; \
        U.z = wx0*TA.z + wx1*TB.z + wx2*TC.z + wx3*TD.z; \
        U.w = wx0*TA.w + wx1*TB.w + wx2*TC.w + wx3*TD.w;
        UCOMB(t00, t01, t02, t03, U0)
        UCOMB(t10, t11, t12, t13, U1)
        UCOMB(t20, t21, t22, t23, U2)
        UCOMB(t30, t31, t32, t33, U3)
#undef UCOMB
#define SC(A, W0, W1, W2, W3) { \
        A.x += W0*U0.x + W1*U1.x + W2*U2.x + W3*U3.x; \
        A.y += W0*U0.y + W1*U1.y + W2*U2.y + W3*U3.y; \
        A.z += W0*U0.z + W1*U1.z + W2*U2.z + W3*U3.z; \
        A.w += W0*U0.w + W1*U1.w + W2*U2.w + W3*U3.w; }
        SC(a0, wa0.x, wa1.x, wa2.x, wa3.x)
        SC(a1, wa0.y, wa1.y, wa2.y, wa3.y)
        SC(a2, wa0.z, wa1.z, wa2.z, wa3.z)
        SC(a3, wa0.w, wa1.w, wa2.w, wa3.w)
        SC(a4, wb0.x, wb1.x, wb2.x, wb3.x)
        SC(a5, wb0.y, wb1.y, wb2.y, wb3.y)
        SC(a6, wb0.z, wb1.z, wb2.z, wb3.z)
#undef SC
    }

    unsigned short* vp = vox + (size_t)p * KDIM;
#define PK(A) make_uint2((unsigned)f2bf(A.x) | ((unsigned)f2bf(A.y) << 16), \
                         (unsigned)f2bf(A.z) | ((unsigned)f2bf(A.w) << 16))
    *(uint2*)(vp + 0 * 256 + lo) = PK(a0);
    *(uint2*)(vp + 1 * 256 + lo) = PK(a1);
    *(uint2*)(vp + 2 * 256 + lo) = PK(a2);
    *(uint2*)(vp + 3 * 256 + lo) = PK(a3);
    *(uint2*)(vp + 4 * 256 + lo) = PK(a4);
    *(uint2*)(vp + 5 * 256 + lo) = PK(a5);
    *(uint2*)(vp + 6 * 256 + lo) = PK(a6);
#undef PK
}

// ---------------- K3b: GEMM vox(bf16) x B2 -> out, M-tile 64 ----------------
__global__ __launch_bounds__(256, 2) void k_mm(
    const unsigned short* __restrict__ vox, const unsigned short* __restrict__ B2,
    const float* __restrict__ bias, float* __restrict__ out)
{
    __shared__ unsigned short As[64][268];
    const int tid = threadIdx.x, lane = tid & 63, wv = tid >> 6;
    const int b = blockIdx.x;
    const int L = (b & 7) * 50 + (b >> 3);   // 400 = 8 x 50
    const int p0 = L * 64;
    const int q = lane >> 4, r = lane & 15;

    floatx4 acc[4][4];
#pragma unroll
    for (int mt = 0; mt < 4; ++mt)
#pragma unroll
        for (int nt = 0; nt < 4; ++nt) acc[mt][nt] = (floatx4){0.f, 0.f, 0.f, 0.f};

    const int srow = tid >> 5, scol = (tid & 31) * 8;
    for (int kk = 0; kk < 7; ++kk) {
        // stage 64 x 256 bf16 chunk of vox
#pragma unroll
        for (int r8 = 0; r8 < 8; ++r8) {
            const int row = r8 * 8 + srow;
            int pg = p0 + row; if (pg > NPR - 1) pg = NPR - 1;
            const float4 v = *(const float4*)(vox + (size_t)pg * KDIM + kk * 256 + scol);
            *(float4*)&As[row][scol] = v;
        }
        __syncthreads();
#pragma unroll
        for (int ks = 0; ks < 8; ++ks) {
            short8 af[4], bf[4];
#pragma unroll
            for (int mt = 0; mt < 4; ++mt)
                af[mt] = *(const short8*)&As[mt * 16 + r][ks * 32 + q * 8];
#pragma unroll
            for (int nt = 0; nt < 4; ++nt)
                bf[nt] = *(const short8*)(B2 + (size_t)((((kk * 8 + ks) * 16) + (wv * 4 + nt)) * 64 + lane) * 8);
#pragma unroll
            for (int mt = 0; mt < 4; ++mt)
#pragma unroll
                for (int nt = 0; nt < 4; ++nt)
                    acc[mt][nt] = __builtin_amdgcn_mfma_f32_16x16x32_bf16(af[mt], bf[nt], acc[mt][nt], 0, 0, 0);
        }
        __syncthreads();
    }

#pragma unroll
    for (int nt = 0; nt < 4; ++nt) {
        const int co = wv * 64 + nt * 16 + r;
        const float bs = bias[co];
#pragma unroll
        for (int mt = 0; mt < 4; ++mt) {
            const int pb = p0 + mt * 16 + q * 4;
            float* op = out + (size_t)co * NP + pb;
            if (pb + 4 <= NP) {
                f4u vv;
                vv.x = fmaxf(acc[mt][nt][0] + bs, 0.f);
                vv.y = fmaxf(acc[mt][nt][1] + bs, 0.f);
                vv.z = fmaxf(acc[mt][nt][2] + bs, 0.f);
                vv.w = fmaxf(acc[mt][nt][3] + bs, 0.f);
                *(f4u*)op = vv;
            } else {
#pragma unroll
                for (int e2 = 0; e2 < 4; ++e2)
                    if (pb + e2 < NP) op[e2] = fmaxf(acc[mt][nt][e2] + bs, 0.f);
            }
        }
    }
}

// ---------------- fallback fused kernel (R4 lineage, folded weights) ----------------
__device__ __forceinline__ float4 gather_row_fb(
    const float* __restrict__ iit, int lane,
    const int4* __restrict__ XTc, const float4* __restrict__ XTw,
    const int4* __restrict__ YTc, const float4* __restrict__ YTw,
    int p, int kc)
{
    const int pl = (p < NP) ? p : (NP - 1);
    const int4  xc = XTc[pl];
    const float4 xw = XTw[pl];
    const int dd = (int)((unsigned)pl / 159u);
    const int4  yc = YTc[dd * NCELL + kc];
    const float4 yw = YTw[dd * NCELL + kc];
    const int r0 = rfl(yc.x), r1 = rfl(yc.y), r2 = rfl(yc.z), r3 = rfl(yc.w);
    const int c0 = rfl(xc.x), c1 = rfl(xc.y), c2 = rfl(xc.z), c3 = rfl(xc.w);
    const float keep = (p < NP) ? 1.f : 0.f;
    const float wy0 = rflf(yw.x) * keep, wy1 = rflf(yw.y) * keep, wy2 = rflf(yw.z) * keep, wy3 = rflf(yw.w) * keep;
    const float wx0 = rflf(xw.x), wx1 = rflf(xw.y), wx2 = rflf(xw.z), wx3 = rflf(xw.w);
    const int lo = lane * 4;
    const float* q00 = iit + (size_t)(r0 * FW + c0) * FC + lo;
    const float* q01 = iit + (size_t)(r0 * FW + c1) * FC + lo;
    const float* q02 = iit + (size_t)(r0 * FW + c2) * FC + lo;
    const float* q03 = iit + (size_t)(r0 * FW + c3) * FC + lo;
    const float* q10 = iit + (size_t)(r1 * FW + c0) * FC + lo;
    const float* q11 = iit + (size_t)(r1 * FW + c1) * FC + lo;
    const float* q12 = iit + (size_t)(r1 * FW + c2) * FC + lo;
    const float* q13 = iit + (size_t)(r1 * FW + c3) * FC + lo;
    const float* q20 = iit + (size_t)(r2 * FW + c0) * FC + lo;
    const float* q21 = iit + (size_t)(r2 * FW + c1) * FC + lo;
    const float* q22 = iit + (size_t)(r2 * FW + c2) * FC + lo;
    const float* q23 = iit + (size_t)(r2 * FW + c3) * FC + lo;
    const float* q30 = iit + (size_t)(r3 * FW + c0) * FC + lo;
    const float* q31 = iit + (size_t)(r3 * FW + c1) * FC + lo;
    const float* q32 = iit + (size_t)(r3 * FW + c2) * FC + lo;
    const float* q33 = iit + (size_t)(r3 * FW + c3) * FC + lo;
    const float4 t00 = *(const float4*)q00;
    const float4 t01 = *(const float4*)q01;
    const float4 t02 = *(const float4*)q02;
    const float4 t03 = *(const float4*)q03;
    const float4 t10 = *(const float4*)q10;
    const float4 t11 = *(const float4*)q11;
    const float4 t12 = *(const float4*)q12;
    const float4 t13 = *(const float4*)q13;
    const float4 t20 = *(const float4*)q20;
    const float4 t21 = *(const float4*)q21;
    const float4 t22 = *(const float4*)q22;
    const float4 t23 = *(const float4*)q23;
    const float4 t30 = *(const float4*)q30;
    const float4 t31 = *(const float4*)q31;
    const float4 t32 = *(const float4*)q32;
    const float4 t33 = *(const float4*)q33;
    float4 a = make_float4(0.f, 0.f, 0.f, 0.f);
#define ACC(T, WY, WX) { const float wt = (WY) * (WX); \
        a.x += wt * T.x; a.y += wt * T.y; a.z += wt * T.z; a.w += wt * T.w; }
    ACC(t00, wy0, wx0) ACC(t01, wy0, wx1) ACC(t02, wy0, wx2) ACC(t03, wy0, wx3)
    ACC(t10, wy1, wx0) ACC(t11, wy1, wx1) ACC(t12, wy1, wx2) ACC(t13, wy1, wx3)
    ACC(t20, wy2, wx0) ACC(t21, wy2, wx1) ACC(t22, wy2, wx2) ACC(t23, wy2, wx3)
    ACC(t30, wy3, wx0) ACC(t31, wy3, wx1) ACC(t32, wy3, wx2) ACC(t33, wy3, wx3)
#undef ACC
    return a;
}

__global__ __launch_bounds__(256, 4) void k_fusedC(
    const float* __restrict__ iit, const unsigned short* __restrict__ B2,
    const int4* __restrict__ XTc, const float4* __restrict__ XTw,
    const int4* __restrict__ YTc, const float4* __restrict__ YTw,
    const float* __restrict__ bias, float* __restrict__ out)
{
    __shared__ unsigned short As[32][264];
    const int tid = threadIdx.x, lane = tid & 63, wv = tid >> 6;
    const int b = blockIdx.x;
    const int L = (b & 7) * 99 + (b >> 3);
    const int p0 = L * 32;
    const int q = lane >> 4, r = lane & 15;

    floatx4 acc[2][4];
#pragma unroll
    for (int mt = 0; mt < 2; ++mt)
#pragma unroll
        for (int nt = 0; nt < 4; ++nt) acc[mt][nt] = (floatx4){0.f, 0.f, 0.f, 0.f};

    for (int kc = 0; kc < NCELL; ++kc) {
#pragma unroll 1
        for (int i = 0; i < 8; ++i) {
            const int pr = wv * 8 + i;
            const float4 a = gather_row_fb(iit, lane, XTc, XTw, YTc, YTw, p0 + pr, kc);
            *(uint2*)&As[pr][lane * 4] = make_uint2(
                (unsigned)f2bf(a.x) | ((unsigned)f2bf(a.y) << 16),
                (unsigned)f2bf(a.z) | ((unsigned)f2bf(a.w) << 16));
        }
        __syncthreads();
#pragma unroll
        for (int ks = 0; ks < 8; ++ks) {
            short8 af[2], bf[4];
#pragma unroll
            for (int mt = 0; mt < 2; ++mt)
                af[mt] = *(const short8*)&As[mt * 16 + r][ks * 32 + q * 8];
#pragma unroll
            for (int nt = 0; nt < 4; ++nt)
                bf[nt] = *(const short8*)(B2 + (size_t)((((kc * 8 + ks) * 16) + (wv * 4 + nt)) * 64 + lane) * 8);
#pragma unroll
            for (int mt = 0; mt < 2; ++mt)
#pragma unroll
                for (int nt = 0; nt < 4; ++nt)
                    acc[mt][nt] = __builtin_amdgcn_mfma_f32_16x16x32_bf16(af[mt], bf[nt], acc[mt][nt], 0, 0, 0);
        }
        __syncthreads();
    }

#pragma unroll
    for (int nt = 0; nt < 4; ++nt) {
        const int co = wv * 64 + nt * 16 + r;
        const float bs = bias[co];
#pragma unroll
        for (int mt = 0; mt < 2; ++mt) {
            const int pb = p0 + mt * 16 + q * 4;
            float* op = out + (size_t)co * NP + pb;
            if (pb + 4 <= NP) {
                f4u vv;
                vv.x = fmaxf(acc[mt][nt][0] + bs, 0.f);
                vv.y = fmaxf(acc[mt][nt][1] + bs, 0.f);
                vv.z = fmaxf(acc[mt][nt][2] + bs, 0.f);
                vv.w = fmaxf(acc[mt][nt][3] + bs, 0.f);
                *(f4u*)op = vv;
            } else {
#pragma unroll
                for (int e2 = 0; e2 < 4; ++e2)
                    if (pb + e2 < NP) op[e2] = fmaxf(acc[mt][nt][e2] + bs, 0.f);
            }
        }
    }
}

// ---------------- launch ----------------
extern "C" void kernel_launch(void* const* d_in, const int* in_sizes, int n_in,
                              void* d_out, int out_size, void* d_ws, size_t ws_size,
                              hipStream_t stream) {
    (void)in_sizes; (void)n_in; (void)out_size;
    const float* features = (const float*)d_in[0];
    const float* W_lin    = (const float*)d_in[4];
    const float* b_lin    = (const float*)d_in[5];
    float* out = (float*)d_out;
    char* ws = (char*)d_ws;

    float*          iit = (float*)(ws + 0);                 // 30,670,848
    unsigned short* B2  = (unsigned short*)(ws + 30670848); //    917,504 -> 31,588,352
    int4*   XTc = (int4*)  (ws + 31588352);                 //    405,504 -> 31,993,856
    float4* XTw = (float4*)(ws + 31993856);                 //    405,504 -> 32,399,360
    float*  YRt = (float*) (ws + 32399360);                 //    142,464 -> 32,541,824
    int*    Rd  = (int*)   (ws + 32541824);                 //        640 -> 32,542,464
    int4*   YTc = (int4*)  (ws + 32542464);                 //     17,920 -> 32,560,384
    float4* YTw = (float4*)(ws + 32560384);                 //     17,920 -> 32,578,304
    unsigned short* vox = (unsigned short*)(ws + 32578304); // 90,832,896 -> 123,411,200

    k_xscanT<<<dim3(96, 8), 256, 0, stream>>>(features, iit);
    k_ysum  <<<312, 256, 0, stream>>>(iit);
    k_prep  <<<1936, 256, 0, stream>>>(W_lin, B2, XTc, XTw, YRt, Rd, YTc, YTw);

    if (ws_size >= 123411200ull) {
        k_gather<<<6336, 256, 0, stream>>>(iit, XTc, XTw, YRt, Rd, vox);
        k_mm    <<<400, 256, 0, stream>>>(vox, B2, b_lin, out);
    } else {
        k_fusedC<<<792, 256, 0, stream>>>(iit, B2, XTc, XTw, YTc, YTw, b_lin, out);
    }
}